// Round 1
// baseline (1464.484 us; speedup 1.0000x reference)
//
#include <hip/hip_runtime.h>
#include <hip/hip_bf16.h>
#include <stdint.h>

#define TT   8192   // B*S tokens
#define DD   2048
#define MM   2048
#define NE   8

typedef float f32x4 __attribute__((ext_vector_type(4)));
typedef short s16x8 __attribute__((ext_vector_type(8)));

static __device__ __forceinline__ short f2bf(float f) {
  __hip_bfloat16 h = __float2bfloat16(f);
  short s;
  __builtin_memcpy(&s, &h, 2);
  return s;
}

// ---------------- fp32 -> bf16 conversion ----------------
__global__ __launch_bounds__(256) void cvt_kernel(const float* __restrict__ in,
                                                  short* __restrict__ out, size_t n) {
  size_t idx = ((size_t)blockIdx.x * 256 + threadIdx.x) * 8;
  size_t stride = (size_t)gridDim.x * 256 * 8;
  for (size_t i = idx; i < n; i += stride) {
    f32x4 a = *(const f32x4*)(in + i);
    f32x4 b = *(const f32x4*)(in + i + 4);
    s16x8 v;
    v[0]=f2bf(a[0]); v[1]=f2bf(a[1]); v[2]=f2bf(a[2]); v[3]=f2bf(a[3]);
    v[4]=f2bf(b[0]); v[5]=f2bf(b[1]); v[6]=f2bf(b[2]); v[7]=f2bf(b[3]);
    *(s16x8*)(out + i) = v;
  }
}

// ---------------- gate: fp32 logits, top-2, softmax ----------------
__global__ __launch_bounds__(256) void gate_kernel(const float* __restrict__ x,
    const float* __restrict__ gk, int* __restrict__ counts,
    int* __restrict__ tkidx, float* __restrict__ tkw) {
  int t = blockIdx.x;
  const float* xr = x + (size_t)t * DD;
  float acc[NE];
  #pragma unroll
  for (int e = 0; e < NE; e++) acc[e] = 0.f;
  for (int d = threadIdx.x; d < DD; d += 256) {
    float xv = xr[d];
    const float* g = gk + (size_t)d * NE;
    #pragma unroll
    for (int e = 0; e < NE; e++) acc[e] += xv * g[e];
  }
  #pragma unroll
  for (int e = 0; e < NE; e++) {
    #pragma unroll
    for (int off = 32; off >= 1; off >>= 1)
      acc[e] += __shfl_xor(acc[e], off, 64);
  }
  __shared__ float red[4][NE];
  int wid = threadIdx.x >> 6;
  int lane = threadIdx.x & 63;
  if (lane == 0) {
    #pragma unroll
    for (int e = 0; e < NE; e++) red[wid][e] = acc[e];
  }
  __syncthreads();
  if (threadIdx.x == 0) {
    float l[NE];
    #pragma unroll
    for (int e = 0; e < NE; e++) l[e] = red[0][e] + red[1][e] + red[2][e] + red[3][e];
    int i1 = 0; float v1 = l[0];
    #pragma unroll
    for (int e = 1; e < NE; e++) if (l[e] > v1) { v1 = l[e]; i1 = e; }
    int i2 = -1; float v2 = -1e30f;
    #pragma unroll
    for (int e = 0; e < NE; e++) if (e != i1 && l[e] > v2) { v2 = l[e]; i2 = e; }
    float p = __expf(v2 - v1);           // v1 >= v2
    float inv = 1.f / (1.f + p);
    tkidx[t*2]   = i1; tkidx[t*2+1] = i2;
    tkw[t*2]     = inv; tkw[t*2+1]  = p * inv;
    atomicAdd(&counts[i1], 1);
    atomicAdd(&counts[i2], 1);
  }
}

// ---------------- scatter into per-expert compact lists ----------------
__global__ __launch_bounds__(256) void scatter_kernel(const int* __restrict__ counts,
    int* __restrict__ offsets, const int* __restrict__ tkidx,
    const float* __restrict__ tkw, int* __restrict__ ltok, float* __restrict__ lwt) {
  __shared__ int soff[NE];
  __shared__ int scur[NE];
  if (threadIdx.x == 0) {
    int s = 0;
    for (int e = 0; e < NE; e++) { offsets[e] = s; soff[e] = s; s += counts[e]; scur[e] = 0; }
    offsets[NE] = s;
  }
  __syncthreads();
  for (int i = threadIdx.x; i < TT * 2; i += 256) {
    int e = tkidx[i];
    int pos = atomicAdd(&scur[e], 1);
    int dst = soff[e] + pos;
    ltok[dst] = i >> 1;
    lwt[dst]  = tkw[i];
  }
}

// ---------------- grouped GEMM helpers ----------------
#define BM1 256
#define BN1 128
#define BM2 256
#define BN2 128
#define BK  32
#define LDK 40   // padded LDS k-stride (shorts); 80B rows -> ~2-way read conflicts
#define MAXT 72

__device__ __forceinline__ void find_seg(const int* __restrict__ offsets, int tile, int bm,
                                         int& e, int& row0, int& rows, int& seg) {
  e = -1; row0 = 0; rows = 0; seg = 0;
  int accT = 0, prev = offsets[0];
  #pragma unroll
  for (int i = 0; i < NE; i++) {
    int nxt = offsets[i+1];
    int cnt = nxt - prev;
    int nt = (cnt + bm - 1) / bm;
    if (e < 0 && tile < accT + nt) { e = i; row0 = (tile - accT) * bm; rows = cnt; seg = prev; }
    accT += nt; prev = nxt;
  }
}

// ---------------- GEMM1: h = silu(x@wi0) * (x@wi1) * w  (gathered rows) ----------------
template<bool WB>
__global__ __launch_bounds__(512) void gemm1_kernel(
    const short* __restrict__ xbf,
    const short* __restrict__ w0b, const short* __restrict__ w1b,
    const float* __restrict__ w0f, const float* __restrict__ w1f,
    const int* __restrict__ offsets,
    const int* __restrict__ ltok, const float* __restrict__ lwt,
    short* __restrict__ hbuf) {
  __shared__ short As[BM1][LDK];
  __shared__ short B0s[BN1][LDK];
  __shared__ short B1s[BN1][LDK];
  __shared__ float w_s[BM1];

  const int tile = blockIdx.x;
  const int n0 = blockIdx.y * BN1;
  int e, row0, rows, seg;
  find_seg(offsets, tile, BM1, e, row0, rows, seg);
  if (e < 0) return;

  const int tid = threadIdx.x;
  for (int r = tid; r < BM1; r += 512) {
    int gr = row0 + r;
    w_s[r] = (gr < rows) ? lwt[seg + gr] : 0.f;
  }

  // A staging: 512 thr, 2 per row, 16 k each
  const int ar = tid >> 1;
  const int ak = (tid & 1) * 16;
  const int agr = row0 + ar;
  const int atok = ltok[seg + (agr < rows ? agr : rows - 1)];
  const short* aptr = xbf + (size_t)atok * DD + ak;

  // B staging: 256 thr per matrix, 8 thr per k-row, 16 n each
  const int bmx = tid >> 8;
  const int t2 = tid & 255;
  const int bk = t2 >> 3;
  const int bn = (t2 & 7) * 16;
  const size_t widx = ((size_t)e * DD + bk) * MM + n0 + bn;
  const short* wsb = (bmx == 0 ? w0b : w1b) ? (bmx == 0 ? w0b : w1b) + widx : nullptr;
  const float* wsf = (bmx == 0 ? w0f : w1f) ? (bmx == 0 ? w0f : w1f) + widx : nullptr;
  short* bdst = (bmx == 0 ? &B0s[0][0] : &B1s[0][0]);

  const int wid = tid >> 6, lane = tid & 63;
  const int wr = wid >> 1, wc = wid & 1;       // 4x2 waves, wave tile 64x64
  const int lr = lane & 15, kh = (lane >> 4) * 8;

  f32x4 acc0[4][4], acc1[4][4];
  #pragma unroll
  for (int i = 0; i < 4; i++)
    #pragma unroll
    for (int j = 0; j < 4; j++) { acc0[i][j] = 0.f; acc1[i][j] = 0.f; }

  for (int k0 = 0; k0 < DD; k0 += BK) {
    s16x8 a0 = *(const s16x8*)(aptr + k0);
    s16x8 a1 = *(const s16x8*)(aptr + k0 + 8);
    short tmp[16];
    if constexpr (WB) {
      s16x8 b0v = *(const s16x8*)(wsb + (size_t)k0 * MM);
      s16x8 b1v = *(const s16x8*)(wsb + (size_t)k0 * MM + 8);
      #pragma unroll
      for (int j = 0; j < 8; j++) { tmp[j] = b0v[j]; tmp[8+j] = b1v[j]; }
    } else {
      const float* p = wsf + (size_t)k0 * MM;
      f32x4 c0 = *(const f32x4*)(p);
      f32x4 c1 = *(const f32x4*)(p + 4);
      f32x4 c2 = *(const f32x4*)(p + 8);
      f32x4 c3 = *(const f32x4*)(p + 12);
      #pragma unroll
      for (int j = 0; j < 4; j++) {
        tmp[j] = f2bf(c0[j]); tmp[4+j] = f2bf(c1[j]);
        tmp[8+j] = f2bf(c2[j]); tmp[12+j] = f2bf(c3[j]);
      }
    }
    *(s16x8*)&As[ar][ak]     = a0;
    *(s16x8*)&As[ar][ak + 8] = a1;
    #pragma unroll
    for (int j = 0; j < 16; j++) bdst[(bn + j) * LDK + bk] = tmp[j];
    __syncthreads();

    s16x8 af[4], b0f[4], b1f[4];
    #pragma unroll
    for (int mi = 0; mi < 4; mi++) af[mi] = *(const s16x8*)&As[wr*64 + mi*16 + lr][kh];
    #pragma unroll
    for (int ni = 0; ni < 4; ni++) {
      b0f[ni] = *(const s16x8*)&B0s[wc*64 + ni*16 + lr][kh];
      b1f[ni] = *(const s16x8*)&B1s[wc*64 + ni*16 + lr][kh];
    }
    #pragma unroll
    for (int mi = 0; mi < 4; mi++)
      #pragma unroll
      for (int ni = 0; ni < 4; ni++) {
        acc0[mi][ni] = __builtin_amdgcn_mfma_f32_16x16x32_bf16(af[mi], b0f[ni], acc0[mi][ni], 0, 0, 0);
        acc1[mi][ni] = __builtin_amdgcn_mfma_f32_16x16x32_bf16(af[mi], b1f[ni], acc1[mi][ni], 0, 0, 0);
      }
    __syncthreads();
  }

  const int lq = lane >> 4;
  #pragma unroll
  for (int mi = 0; mi < 4; mi++) {
    #pragma unroll
    for (int jj = 0; jj < 4; jj++) {
      int r = wr*64 + mi*16 + lq*4 + jj;
      int gr = row0 + r;
      if (gr < rows) {
        float wgt = w_s[r];
        size_t hrow = (size_t)(seg + gr) * MM + n0;
        #pragma unroll
        for (int ni = 0; ni < 4; ni++) {
          int c = wc*64 + ni*16 + lr;
          float g = acc0[mi][ni][jj];
          float u = acc1[mi][ni][jj];
          float act = g / (1.f + __expf(-g));
          hbuf[hrow + c] = f2bf(act * u * wgt);
        }
      }
    }
  }
}

// ---------------- GEMM2: out[tok] += h @ wo[e] ----------------
template<bool WB>
__global__ __launch_bounds__(256) void gemm2_kernel(
    const short* __restrict__ hbuf,
    const short* __restrict__ wob, const float* __restrict__ wof,
    const int* __restrict__ offsets,
    const int* __restrict__ ltok,
    float* __restrict__ out) {
  __shared__ short As[BM2][LDK];
  __shared__ short Bs[BN2][LDK];
  __shared__ int tok_s[BM2];

  const int tile = blockIdx.x;
  const int n0 = blockIdx.y * BN2;
  int e, row0, rows, seg;
  find_seg(offsets, tile, BM2, e, row0, rows, seg);
  if (e < 0) return;

  const int tid = threadIdx.x;
  for (int r = tid; r < BM2; r += 256) {
    int gr = row0 + r;
    tok_s[r] = (gr < rows) ? ltok[seg + gr] : -1;
  }

  const int agr = row0 + tid;
  const size_t arow = (size_t)(seg + (agr < rows ? agr : rows - 1)) * MM;

  const int bk = tid >> 3;
  const int bn = (tid & 7) * 16;
  const size_t widx = ((size_t)e * MM + bk) * DD + n0 + bn;

  const int wid = tid >> 6, lane = tid & 63;
  const int wr = wid >> 1, wc = wid & 1;       // 2x2 waves, wave tile 128x64
  const int lr = lane & 15, kh = (lane >> 4) * 8;

  f32x4 acc[8][4];
  #pragma unroll
  for (int i = 0; i < 8; i++)
    #pragma unroll
    for (int j = 0; j < 4; j++) acc[i][j] = 0.f;

  for (int k0 = 0; k0 < MM; k0 += BK) {
    s16x8 a0 = *(const s16x8*)(hbuf + arow + k0);
    s16x8 a1 = *(const s16x8*)(hbuf + arow + k0 + 8);
    s16x8 a2 = *(const s16x8*)(hbuf + arow + k0 + 16);
    s16x8 a3 = *(const s16x8*)(hbuf + arow + k0 + 24);
    short tmp[16];
    if constexpr (WB) {
      s16x8 b0v = *(const s16x8*)(wob + widx + (size_t)k0 * DD);
      s16x8 b1v = *(const s16x8*)(wob + widx + (size_t)k0 * DD + 8);
      #pragma unroll
      for (int j = 0; j < 8; j++) { tmp[j] = b0v[j]; tmp[8+j] = b1v[j]; }
    } else {
      const float* p = wof + widx + (size_t)k0 * DD;
      f32x4 c0 = *(const f32x4*)(p);
      f32x4 c1 = *(const f32x4*)(p + 4);
      f32x4 c2 = *(const f32x4*)(p + 8);
      f32x4 c3 = *(const f32x4*)(p + 12);
      #pragma unroll
      for (int j = 0; j < 4; j++) {
        tmp[j] = f2bf(c0[j]); tmp[4+j] = f2bf(c1[j]);
        tmp[8+j] = f2bf(c2[j]); tmp[12+j] = f2bf(c3[j]);
      }
    }
    *(s16x8*)&As[tid][0]  = a0;
    *(s16x8*)&As[tid][8]  = a1;
    *(s16x8*)&As[tid][16] = a2;
    *(s16x8*)&As[tid][24] = a3;
    #pragma unroll
    for (int j = 0; j < 16; j++) Bs[bn + j][bk] = tmp[j];
    __syncthreads();

    s16x8 af[8], bf_[4];
    #pragma unroll
    for (int mi = 0; mi < 8; mi++) af[mi] = *(const s16x8*)&As[wr*128 + mi*16 + lr][kh];
    #pragma unroll
    for (int ni = 0; ni < 4; ni++) bf_[ni] = *(const s16x8*)&Bs[wc*64 + ni*16 + lr][kh];
    #pragma unroll
    for (int mi = 0; mi < 8; mi++)
      #pragma unroll
      for (int ni = 0; ni < 4; ni++)
        acc[mi][ni] = __builtin_amdgcn_mfma_f32_16x16x32_bf16(af[mi], bf_[ni], acc[mi][ni], 0, 0, 0);
    __syncthreads();
  }

  const int lq = lane >> 4;
  #pragma unroll
  for (int mi = 0; mi < 8; mi++) {
    #pragma unroll
    for (int jj = 0; jj < 4; jj++) {
      int r = wr*128 + mi*16 + lq*4 + jj;
      int gr = row0 + r;
      if (gr < rows) {
        size_t orow = (size_t)tok_s[r] * DD + n0;
        #pragma unroll
        for (int ni = 0; ni < 4; ni++) {
          int c = wc*64 + ni*16 + lr;
          atomicAdd(&out[orow + c], acc[mi][ni][jj]);
        }
      }
    }
  }
}

// ---------------- launcher ----------------
extern "C" void kernel_launch(void* const* d_in, const int* in_sizes, int n_in,
                              void* d_out, int out_size, void* d_ws, size_t ws_size,
                              hipStream_t stream) {
  const float* x   = (const float*)d_in[0];
  const float* gk  = (const float*)d_in[1];
  const float* wi0 = (const float*)d_in[2];
  const float* wi1 = (const float*)d_in[3];
  const float* wo  = (const float*)d_in[4];
  float* out = (float*)d_out;

  char* w = (char*)d_ws;
  int*   counts  = (int*)(w);
  int*   offsets = (int*)(w + 256);
  int*   tkidx   = (int*)(w + 1024);
  float* tkw     = (float*)(w + 1024 + 65536);
  int*   ltok    = (int*)(w + 1024 + 2*65536);
  float* lwt     = (float*)(w + 1024 + 3*65536);
  short* xbf  = (short*)(w + 524288);
  short* hbuf = xbf + (size_t)TT * DD;                     // 2T x M bf16
  short* w0b  = hbuf + (size_t)2 * TT * MM;
  short* w1b  = w0b + (size_t)NE * DD * MM;
  short* wob  = w1b + (size_t)NE * DD * MM;
  const size_t FULL_NEED = 524288ull + (size_t)TT*DD*2 + (size_t)2*TT*MM*2 + 3ull*NE*DD*MM*2;
  const bool wb = (ws_size >= FULL_NEED);

  hipMemsetAsync(counts, 0, 64, stream);
  hipMemsetAsync(out, 0, sizeof(float) * (size_t)out_size, stream);

  cvt_kernel<<<1024, 256, 0, stream>>>(x, xbf, (size_t)TT * DD);
  if (wb) {
    cvt_kernel<<<2048, 256, 0, stream>>>(wi0, w0b, (size_t)NE * DD * MM);
    cvt_kernel<<<2048, 256, 0, stream>>>(wi1, w1b, (size_t)NE * DD * MM);
    cvt_kernel<<<2048, 256, 0, stream>>>(wo,  wob, (size_t)NE * MM * DD);
  }
  gate_kernel<<<TT, 256, 0, stream>>>(x, gk, counts, tkidx, tkw);
  scatter_kernel<<<1, 256, 0, stream>>>(counts, offsets, tkidx, tkw, ltok, lwt);

  dim3 g1(MAXT, MM / BN1), g2(MAXT, DD / BN2);
  if (wb) {
    gemm1_kernel<true><<<g1, 512, 0, stream>>>(xbf, w0b, w1b, nullptr, nullptr,
                                               offsets, ltok, lwt, hbuf);
    gemm2_kernel<true><<<g2, 256, 0, stream>>>(hbuf, wob, nullptr, offsets, ltok, out);
  } else {
    gemm1_kernel<false><<<g1, 512, 0, stream>>>(xbf, nullptr, nullptr, wi0, wi1,
                                                offsets, ltok, lwt, hbuf);
    gemm2_kernel<false><<<g2, 256, 0, stream>>>(hbuf, nullptr, wo, offsets, ltok, out);
  }
}

// Round 3
// 937.187 us; speedup vs baseline: 1.5626x; 1.5626x over previous
//
#include <hip/hip_runtime.h>
#include <hip/hip_bf16.h>
#include <stdint.h>

#define TT   8192   // B*S tokens
#define DD   2048
#define MM   2048
#define NE   8

typedef float f32x4 __attribute__((ext_vector_type(4)));
typedef short s16x8 __attribute__((ext_vector_type(8)));
typedef short s16x4 __attribute__((ext_vector_type(4)));
typedef unsigned int u32;

static __device__ __forceinline__ short f2bf(float f) {
  __hip_bfloat16 h = __float2bfloat16(f);
  short s;
  __builtin_memcpy(&s, &h, 2);
  return s;
}

static __device__ __forceinline__ void gload_lds16(const short* g, short* lds) {
  __builtin_amdgcn_global_load_lds(
      (const __attribute__((address_space(1))) u32*)g,
      (__attribute__((address_space(3))) u32*)lds, 16, 0, 0);
}

// ---------------- fp32 -> bf16 conversion (x) ----------------
__global__ __launch_bounds__(256) void cvt_kernel(const float* __restrict__ in,
                                                  short* __restrict__ out, size_t n) {
  size_t idx = ((size_t)blockIdx.x * 256 + threadIdx.x) * 8;
  size_t stride = (size_t)gridDim.x * 256 * 8;
  for (size_t i = idx; i < n; i += stride) {
    f32x4 a = *(const f32x4*)(in + i);
    f32x4 b = *(const f32x4*)(in + i + 4);
    s16x8 v;
    v[0]=f2bf(a[0]); v[1]=f2bf(a[1]); v[2]=f2bf(a[2]); v[3]=f2bf(a[3]);
    v[4]=f2bf(b[0]); v[5]=f2bf(b[1]); v[6]=f2bf(b[2]); v[7]=f2bf(b[3]);
    *(s16x8*)(out + i) = v;
  }
}

// ---------------- fp32 -> bf16 transposing conversion (weights) ----------------
// in: [E][2048][2048] f32 (k-major). out: [E][2048][2048] bf16 transposed (n-major).
__global__ __launch_bounds__(256) void tcvt_kernel(
    const float* __restrict__ w0, const float* __restrict__ w1, const float* __restrict__ w2,
    short* __restrict__ o0, short* __restrict__ o1, short* __restrict__ o2) {
  __shared__ short tile[64][65];
  const int bz = blockIdx.z;                 // 0..23: weight = bz>>3, expert = bz&7
  const float* in; short* out;
  if (bz < 8)       { in = w0; out = o0; }
  else if (bz < 16) { in = w1; out = o1; }
  else              { in = w2; out = o2; }
  const int ex = bz & 7;
  const float* src = in + (size_t)ex * DD * MM;
  short* dst = out + (size_t)ex * DD * MM;
  const int r0 = blockIdx.y * 64;            // source row (k)
  const int c0 = blockIdx.x * 64;            // source col (n)
  const int t = threadIdx.x;
  const int rr = t >> 4, cc = (t & 15) * 4;
  #pragma unroll
  for (int i = 0; i < 4; i++) {
    int row = rr + i * 16;
    f32x4 v = *(const f32x4*)(src + (size_t)(r0 + row) * MM + c0 + cc);
    tile[cc + 0][row] = f2bf(v[0]);
    tile[cc + 1][row] = f2bf(v[1]);
    tile[cc + 2][row] = f2bf(v[2]);
    tile[cc + 3][row] = f2bf(v[3]);
  }
  __syncthreads();
  #pragma unroll
  for (int i = 0; i < 4; i++) {
    int orow = rr + i * 16;                  // = source col
    s16x4 v;
    v[0] = tile[orow][cc + 0]; v[1] = tile[orow][cc + 1];
    v[2] = tile[orow][cc + 2]; v[3] = tile[orow][cc + 3];
    *(s16x4*)(dst + (size_t)(c0 + orow) * DD + r0 + cc) = v;
  }
}

// ---------------- gate: fp32 logits, top-2, softmax ----------------
__global__ __launch_bounds__(256) void gate_kernel(const float* __restrict__ x,
    const float* __restrict__ gk, int* __restrict__ counts,
    int* __restrict__ tkidx, float* __restrict__ tkw) {
  int t = blockIdx.x;
  const float* xr = x + (size_t)t * DD;
  float acc[NE];
  #pragma unroll
  for (int e = 0; e < NE; e++) acc[e] = 0.f;
  for (int d = threadIdx.x; d < DD; d += 256) {
    float xv = xr[d];
    const float* g = gk + (size_t)d * NE;
    #pragma unroll
    for (int e = 0; e < NE; e++) acc[e] += xv * g[e];
  }
  #pragma unroll
  for (int e = 0; e < NE; e++) {
    #pragma unroll
    for (int off = 32; off >= 1; off >>= 1)
      acc[e] += __shfl_xor(acc[e], off, 64);
  }
  __shared__ float red[4][NE];
  int wid = threadIdx.x >> 6;
  int lane = threadIdx.x & 63;
  if (lane == 0) {
    #pragma unroll
    for (int e = 0; e < NE; e++) red[wid][e] = acc[e];
  }
  __syncthreads();
  if (threadIdx.x == 0) {
    float l[NE];
    #pragma unroll
    for (int e = 0; e < NE; e++) l[e] = red[0][e] + red[1][e] + red[2][e] + red[3][e];
    int i1 = 0; float v1 = l[0];
    #pragma unroll
    for (int e = 1; e < NE; e++) if (l[e] > v1) { v1 = l[e]; i1 = e; }
    int i2 = -1; float v2 = -1e30f;
    #pragma unroll
    for (int e = 0; e < NE; e++) if (e != i1 && l[e] > v2) { v2 = l[e]; i2 = e; }
    float p = __expf(v2 - v1);           // v1 >= v2
    float inv = 1.f / (1.f + p);
    tkidx[t*2]   = i1; tkidx[t*2+1] = i2;
    tkw[t*2]     = inv; tkw[t*2+1]  = p * inv;
    atomicAdd(&counts[i1], 1);
    atomicAdd(&counts[i2], 1);
  }
}

// ---------------- scatter into per-expert compact lists ----------------
__global__ __launch_bounds__(256) void scatter_kernel(const int* __restrict__ counts,
    int* __restrict__ offsets, const int* __restrict__ tkidx,
    const float* __restrict__ tkw, int* __restrict__ ltok, float* __restrict__ lwt) {
  __shared__ int soff[NE];
  __shared__ int scur[NE];
  if (threadIdx.x == 0) {
    int s = 0;
    for (int e = 0; e < NE; e++) { offsets[e] = s; soff[e] = s; s += counts[e]; scur[e] = 0; }
    offsets[NE] = s;
  }
  __syncthreads();
  for (int i = threadIdx.x; i < TT * 2; i += 256) {
    int e = tkidx[i];
    int pos = atomicAdd(&scur[e], 1);
    int dst = soff[e] + pos;
    ltok[dst] = i >> 1;
    lwt[dst]  = tkw[i];
  }
}

// ---------------- segment lookup ----------------
__device__ __forceinline__ void find_seg(const int* __restrict__ offsets, int tile, int bm,
                                         int& e, int& row0, int& rows, int& seg) {
  e = -1; row0 = 0; rows = 0; seg = 0;
  int accT = 0, prev = offsets[0];
  #pragma unroll
  for (int i = 0; i < NE; i++) {
    int nxt = offsets[i+1];
    int cnt = nxt - prev;
    int nt = (cnt + bm - 1) / bm;
    if (e < 0 && tile < accT + nt) { e = i; row0 = (tile - accT) * bm; rows = cnt; seg = prev; }
    accT += nt; prev = nxt;
  }
}

// ================= FAST PATH (global_load_lds + pre-swizzled source) =================
// 128x128 tile, BK=64, 256 threads (2x2 waves, 64x64 wave tile, 4x4 16x16x32 frags).
// LDS layout linear [128][64] shorts; swizzle: short-offset s holds G[row][s ^ ((row&7)*8)].
#define MAXT_F 136

__global__ __launch_bounds__(256, 2) void gemm1_fast(
    const short* __restrict__ xbf,
    const short* __restrict__ w0t, const short* __restrict__ w1t,
    const int* __restrict__ offsets,
    const int* __restrict__ ltok, const float* __restrict__ lwt,
    short* __restrict__ hbuf) {
  __shared__ short As[128 * 64];
  __shared__ short B0s[128 * 64];
  __shared__ short B1s[128 * 64];
  __shared__ float w_s[128];

  const int tile = blockIdx.x;
  const int n0 = blockIdx.y * 128;
  int e, row0, rows, seg;
  find_seg(offsets, tile, 128, e, row0, rows, seg);
  if (e < 0) return;

  const int tid = threadIdx.x;
  const int lane = tid & 63, wid = tid >> 6;
  if (tid < 128) {
    int gr = row0 + tid;
    w_s[tid] = (gr < rows) ? lwt[seg + gr] : 0.f;
  }

  // staging: wave wid owns chunks wid*4..wid*4+3 of each tile (chunk = 8 rows = 1KB)
  const int swz = ((lane & 7) ^ (lane >> 3)) * 8;   // shorts, pre-swizzled source offset
  const short* abase[4];
  const short* b0base[4];
  const short* b1base[4];
  #pragma unroll
  for (int c = 0; c < 4; c++) {
    int chunk = wid * 4 + c;
    int r = chunk * 8 + (lane >> 3);
    int gr = row0 + r; if (gr >= rows) gr = rows - 1;
    int tok = ltok[seg + gr];
    abase[c]  = xbf + (size_t)tok * DD + swz;
    int n = n0 + r;
    b0base[c] = w0t + ((size_t)e * MM + n) * DD + swz;
    b1base[c] = w1t + ((size_t)e * MM + n) * DD + swz;
  }

  const int wr = wid >> 1, wc = wid & 1;
  const int lr = lane & 15;
  const int kq = (lane >> 4) * 8;                    // k sub-offset (shorts)

  f32x4 acc0[4][4], acc1[4][4];
  #pragma unroll
  for (int i = 0; i < 4; i++)
    #pragma unroll
    for (int j = 0; j < 4; j++) { acc0[i][j] = 0.f; acc1[i][j] = 0.f; }

  for (int k0 = 0; k0 < DD; k0 += 64) {
    #pragma unroll
    for (int c = 0; c < 4; c++) {
      int chunk = wid * 4 + c;
      gload_lds16(abase[c]  + k0, As  + chunk * 512);
      gload_lds16(b0base[c] + k0, B0s + chunk * 512);
      gload_lds16(b1base[c] + k0, B1s + chunk * 512);
    }
    __syncthreads();

    #pragma unroll
    for (int ks = 0; ks < 2; ks++) {
      s16x8 a[4], b0[4], b1[4];
      #pragma unroll
      for (int mi = 0; mi < 4; mi++) {
        int row = wr * 64 + mi * 16 + lr;
        int koff = (ks * 32 + kq) ^ ((row & 7) * 8);
        a[mi] = *(const s16x8*)&As[row * 64 + koff];
      }
      #pragma unroll
      for (int ni = 0; ni < 4; ni++) {
        int row = wc * 64 + ni * 16 + lr;
        int koff = (ks * 32 + kq) ^ ((row & 7) * 8);
        b0[ni] = *(const s16x8*)&B0s[row * 64 + koff];
        b1[ni] = *(const s16x8*)&B1s[row * 64 + koff];
      }
      #pragma unroll
      for (int mi = 0; mi < 4; mi++)
        #pragma unroll
        for (int ni = 0; ni < 4; ni++) {
          acc0[mi][ni] = __builtin_amdgcn_mfma_f32_16x16x32_bf16(a[mi], b0[ni], acc0[mi][ni], 0, 0, 0);
          acc1[mi][ni] = __builtin_amdgcn_mfma_f32_16x16x32_bf16(a[mi], b1[ni], acc1[mi][ni], 0, 0, 0);
        }
    }
    __syncthreads();
  }

  const int lq = lane >> 4;
  #pragma unroll
  for (int mi = 0; mi < 4; mi++) {
    #pragma unroll
    for (int jj = 0; jj < 4; jj++) {
      int r = wr * 64 + mi * 16 + lq * 4 + jj;
      int gr = row0 + r;
      if (gr < rows) {
        float wgt = w_s[r];
        size_t hrow = (size_t)(seg + gr) * MM + n0;
        #pragma unroll
        for (int ni = 0; ni < 4; ni++) {
          int c = wc * 64 + ni * 16 + lr;
          float g = acc0[mi][ni][jj];
          float u = acc1[mi][ni][jj];
          float act = g / (1.f + __expf(-g));
          hbuf[hrow + c] = f2bf(act * u * wgt);
        }
      }
    }
  }
}

__global__ __launch_bounds__(256, 2) void gemm2_fast(
    const short* __restrict__ hbuf,
    const short* __restrict__ wot,
    const int* __restrict__ offsets,
    const int* __restrict__ ltok,
    float* __restrict__ out) {
  __shared__ short As[128 * 64];
  __shared__ short Bs[128 * 64];
  __shared__ int tok_s[128];

  const int tile = blockIdx.x;
  const int n0 = blockIdx.y * 128;
  int e, row0, rows, seg;
  find_seg(offsets, tile, 128, e, row0, rows, seg);
  if (e < 0) return;

  const int tid = threadIdx.x;
  const int lane = tid & 63, wid = tid >> 6;
  if (tid < 128) {
    int gr = row0 + tid;
    tok_s[tid] = (gr < rows) ? ltok[seg + gr] : -1;
  }

  const int swz = ((lane & 7) ^ (lane >> 3)) * 8;
  const short* abase[4];
  const short* bbase[4];
  #pragma unroll
  for (int c = 0; c < 4; c++) {
    int chunk = wid * 4 + c;
    int r = chunk * 8 + (lane >> 3);
    int gr = row0 + r; if (gr >= rows) gr = rows - 1;
    abase[c] = hbuf + (size_t)(seg + gr) * MM + swz;
    int n = n0 + r;
    bbase[c] = wot + ((size_t)e * DD + n) * MM + swz;
  }

  const int wr = wid >> 1, wc = wid & 1;
  const int lr = lane & 15;
  const int kq = (lane >> 4) * 8;

  f32x4 acc[4][4];
  #pragma unroll
  for (int i = 0; i < 4; i++)
    #pragma unroll
    for (int j = 0; j < 4; j++) acc[i][j] = 0.f;

  for (int k0 = 0; k0 < MM; k0 += 64) {
    #pragma unroll
    for (int c = 0; c < 4; c++) {
      int chunk = wid * 4 + c;
      gload_lds16(abase[c] + k0, As + chunk * 512);
      gload_lds16(bbase[c] + k0, Bs + chunk * 512);
    }
    __syncthreads();

    #pragma unroll
    for (int ks = 0; ks < 2; ks++) {
      s16x8 a[4], b[4];
      #pragma unroll
      for (int mi = 0; mi < 4; mi++) {
        int row = wr * 64 + mi * 16 + lr;
        int koff = (ks * 32 + kq) ^ ((row & 7) * 8);
        a[mi] = *(const s16x8*)&As[row * 64 + koff];
      }
      #pragma unroll
      for (int ni = 0; ni < 4; ni++) {
        int row = wc * 64 + ni * 16 + lr;
        int koff = (ks * 32 + kq) ^ ((row & 7) * 8);
        b[ni] = *(const s16x8*)&Bs[row * 64 + koff];
      }
      #pragma unroll
      for (int mi = 0; mi < 4; mi++)
        #pragma unroll
        for (int ni = 0; ni < 4; ni++)
          acc[mi][ni] = __builtin_amdgcn_mfma_f32_16x16x32_bf16(a[mi], b[ni], acc[mi][ni], 0, 0, 0);
    }
    __syncthreads();
  }

  const int lq = lane >> 4;
  #pragma unroll
  for (int mi = 0; mi < 4; mi++) {
    #pragma unroll
    for (int jj = 0; jj < 4; jj++) {
      int r = wr * 64 + mi * 16 + lq * 4 + jj;
      int gr = row0 + r;
      if (gr < rows) {
        size_t orow = (size_t)tok_s[r] * DD + n0;
        #pragma unroll
        for (int ni = 0; ni < 4; ni++) {
          int c = wc * 64 + ni * 16 + lr;
          atomicAdd(&out[orow + c], acc[mi][ni][jj]);
        }
      }
    }
  }
}

// ================= FALLBACK PATH (round-1, fp32 weights from HBM) =================
#define BM1 256
#define BN1 128
#define BM2 256
#define BN2 128
#define BK  32
#define LDK 40
#define MAXT 72

template<bool WB>
__global__ __launch_bounds__(512) void gemm1_kernel(
    const short* __restrict__ xbf,
    const short* __restrict__ w0b, const short* __restrict__ w1b,
    const float* __restrict__ w0f, const float* __restrict__ w1f,
    const int* __restrict__ offsets,
    const int* __restrict__ ltok, const float* __restrict__ lwt,
    short* __restrict__ hbuf) {
  __shared__ short As[BM1][LDK];
  __shared__ short B0s[BN1][LDK];
  __shared__ short B1s[BN1][LDK];
  __shared__ float w_s[BM1];

  const int tile = blockIdx.x;
  const int n0 = blockIdx.y * BN1;
  int e, row0, rows, seg;
  find_seg(offsets, tile, BM1, e, row0, rows, seg);
  if (e < 0) return;

  const int tid = threadIdx.x;
  for (int r = tid; r < BM1; r += 512) {
    int gr = row0 + r;
    w_s[r] = (gr < rows) ? lwt[seg + gr] : 0.f;
  }

  const int ar = tid >> 1;
  const int ak = (tid & 1) * 16;
  const int agr = row0 + ar;
  const int atok = ltok[seg + (agr < rows ? agr : rows - 1)];
  const short* aptr = xbf + (size_t)atok * DD + ak;

  const int bmx = tid >> 8;
  const int t2 = tid & 255;
  const int bk = t2 >> 3;
  const int bn = (t2 & 7) * 16;
  const size_t widx = ((size_t)e * DD + bk) * MM + n0 + bn;
  const short* wsb = (bmx == 0 ? w0b : w1b) ? (bmx == 0 ? w0b : w1b) + widx : nullptr;
  const float* wsf = (bmx == 0 ? w0f : w1f) ? (bmx == 0 ? w0f : w1f) + widx : nullptr;
  short* bdst = (bmx == 0 ? &B0s[0][0] : &B1s[0][0]);

  const int wid = tid >> 6, lane = tid & 63;
  const int wr = wid >> 1, wc = wid & 1;
  const int lr = lane & 15, kh = (lane >> 4) * 8;

  f32x4 acc0[4][4], acc1[4][4];
  #pragma unroll
  for (int i = 0; i < 4; i++)
    #pragma unroll
    for (int j = 0; j < 4; j++) { acc0[i][j] = 0.f; acc1[i][j] = 0.f; }

  for (int k0 = 0; k0 < DD; k0 += BK) {
    s16x8 a0 = *(const s16x8*)(aptr + k0);
    s16x8 a1 = *(const s16x8*)(aptr + k0 + 8);
    short tmp[16];
    if constexpr (WB) {
      s16x8 b0v = *(const s16x8*)(wsb + (size_t)k0 * MM);
      s16x8 b1v = *(const s16x8*)(wsb + (size_t)k0 * MM + 8);
      #pragma unroll
      for (int j = 0; j < 8; j++) { tmp[j] = b0v[j]; tmp[8+j] = b1v[j]; }
    } else {
      const float* p = wsf + (size_t)k0 * MM;
      f32x4 c0 = *(const f32x4*)(p);
      f32x4 c1 = *(const f32x4*)(p + 4);
      f32x4 c2 = *(const f32x4*)(p + 8);
      f32x4 c3 = *(const f32x4*)(p + 12);
      #pragma unroll
      for (int j = 0; j < 4; j++) {
        tmp[j] = f2bf(c0[j]); tmp[4+j] = f2bf(c1[j]);
        tmp[8+j] = f2bf(c2[j]); tmp[12+j] = f2bf(c3[j]);
      }
    }
    *(s16x8*)&As[ar][ak]     = a0;
    *(s16x8*)&As[ar][ak + 8] = a1;
    #pragma unroll
    for (int j = 0; j < 16; j++) bdst[(bn + j) * LDK + bk] = tmp[j];
    __syncthreads();

    s16x8 af[4], b0f[4], b1f[4];
    #pragma unroll
    for (int mi = 0; mi < 4; mi++) af[mi] = *(const s16x8*)&As[wr*64 + mi*16 + lr][kh];
    #pragma unroll
    for (int ni = 0; ni < 4; ni++) {
      b0f[ni] = *(const s16x8*)&B0s[wc*64 + ni*16 + lr][kh];
      b1f[ni] = *(const s16x8*)&B1s[wc*64 + ni*16 + lr][kh];
    }
    #pragma unroll
    for (int mi = 0; mi < 4; mi++)
      #pragma unroll
      for (int ni = 0; ni < 4; ni++) {
        acc0[mi][ni] = __builtin_amdgcn_mfma_f32_16x16x32_bf16(af[mi], b0f[ni], acc0[mi][ni], 0, 0, 0);
        acc1[mi][ni] = __builtin_amdgcn_mfma_f32_16x16x32_bf16(af[mi], b1f[ni], acc1[mi][ni], 0, 0, 0);
      }
    __syncthreads();
  }

  const int lq = lane >> 4;
  #pragma unroll
  for (int mi = 0; mi < 4; mi++) {
    #pragma unroll
    for (int jj = 0; jj < 4; jj++) {
      int r = wr*64 + mi*16 + lq*4 + jj;
      int gr = row0 + r;
      if (gr < rows) {
        float wgt = w_s[r];
        size_t hrow = (size_t)(seg + gr) * MM + n0;
        #pragma unroll
        for (int ni = 0; ni < 4; ni++) {
          int c = wc*64 + ni*16 + lr;
          float g = acc0[mi][ni][jj];
          float u = acc1[mi][ni][jj];
          float act = g / (1.f + __expf(-g));
          hbuf[hrow + c] = f2bf(act * u * wgt);
        }
      }
    }
  }
}

template<bool WB>
__global__ __launch_bounds__(256) void gemm2_kernel(
    const short* __restrict__ hbuf,
    const short* __restrict__ wob, const float* __restrict__ wof,
    const int* __restrict__ offsets,
    const int* __restrict__ ltok,
    float* __restrict__ out) {
  __shared__ short As[BM2][LDK];
  __shared__ short Bs[BN2][LDK];
  __shared__ int tok_s[BM2];

  const int tile = blockIdx.x;
  const int n0 = blockIdx.y * BN2;
  int e, row0, rows, seg;
  find_seg(offsets, tile, BM2, e, row0, rows, seg);
  if (e < 0) return;

  const int tid = threadIdx.x;
  for (int r = tid; r < BM2; r += 256) {
    int gr = row0 + r;
    tok_s[r] = (gr < rows) ? ltok[seg + gr] : -1;
  }

  const int agr = row0 + tid;
  const size_t arow = (size_t)(seg + (agr < rows ? agr : rows - 1)) * MM;

  const int bk = tid >> 3;
  const int bn = (tid & 7) * 16;
  const size_t widx = ((size_t)e * MM + bk) * DD + n0 + bn;

  const int wid = tid >> 6, lane = tid & 63;
  const int wr = wid >> 1, wc = wid & 1;
  const int lr = lane & 15, kh = (lane >> 4) * 8;

  f32x4 acc[8][4];
  #pragma unroll
  for (int i = 0; i < 8; i++)
    #pragma unroll
    for (int j = 0; j < 4; j++) acc[i][j] = 0.f;

  for (int k0 = 0; k0 < MM; k0 += BK) {
    s16x8 a0 = *(const s16x8*)(hbuf + arow + k0);
    s16x8 a1 = *(const s16x8*)(hbuf + arow + k0 + 8);
    s16x8 a2 = *(const s16x8*)(hbuf + arow + k0 + 16);
    s16x8 a3 = *(const s16x8*)(hbuf + arow + k0 + 24);
    short tmp[16];
    if constexpr (WB) {
      s16x8 b0v = *(const s16x8*)(wob + widx + (size_t)k0 * DD);
      s16x8 b1v = *(const s16x8*)(wob + widx + (size_t)k0 * DD + 8);
      #pragma unroll
      for (int j = 0; j < 8; j++) { tmp[j] = b0v[j]; tmp[8+j] = b1v[j]; }
    } else {
      const float* p = wof + widx + (size_t)k0 * DD;
      f32x4 c0 = *(const f32x4*)(p);
      f32x4 c1 = *(const f32x4*)(p + 4);
      f32x4 c2 = *(const f32x4*)(p + 8);
      f32x4 c3 = *(const f32x4*)(p + 12);
      #pragma unroll
      for (int j = 0; j < 4; j++) {
        tmp[j] = f2bf(c0[j]); tmp[4+j] = f2bf(c1[j]);
        tmp[8+j] = f2bf(c2[j]); tmp[12+j] = f2bf(c3[j]);
      }
    }
    *(s16x8*)&As[tid][0]  = a0;
    *(s16x8*)&As[tid][8]  = a1;
    *(s16x8*)&As[tid][16] = a2;
    *(s16x8*)&As[tid][24] = a3;
    #pragma unroll
    for (int j = 0; j < 16; j++) Bs[bn + j][bk] = tmp[j];
    __syncthreads();

    s16x8 af[8], bf_[4];
    #pragma unroll
    for (int mi = 0; mi < 8; mi++) af[mi] = *(const s16x8*)&As[wr*128 + mi*16 + lr][kh];
    #pragma unroll
    for (int ni = 0; ni < 4; ni++) bf_[ni] = *(const s16x8*)&Bs[wc*64 + ni*16 + lr][kh];
    #pragma unroll
    for (int mi = 0; mi < 8; mi++)
      #pragma unroll
      for (int ni = 0; ni < 4; ni++)
        acc[mi][ni] = __builtin_amdgcn_mfma_f32_16x16x32_bf16(af[mi], bf_[ni], acc[mi][ni], 0, 0, 0);
    __syncthreads();
  }

  const int lq = lane >> 4;
  #pragma unroll
  for (int mi = 0; mi < 8; mi++) {
    #pragma unroll
    for (int jj = 0; jj < 4; jj++) {
      int r = wr*128 + mi*16 + lq*4 + jj;
      int gr = row0 + r;
      if (gr < rows) {
        size_t orow = (size_t)tok_s[r] * DD + n0;
        #pragma unroll
        for (int ni = 0; ni < 4; ni++) {
          int c = wc*64 + ni*16 + lr;
          atomicAdd(&out[orow + c], acc[mi][ni][jj]);
        }
      }
    }
  }
}

// ---------------- launcher ----------------
extern "C" void kernel_launch(void* const* d_in, const int* in_sizes, int n_in,
                              void* d_out, int out_size, void* d_ws, size_t ws_size,
                              hipStream_t stream) {
  const float* x   = (const float*)d_in[0];
  const float* gk  = (const float*)d_in[1];
  const float* wi0 = (const float*)d_in[2];
  const float* wi1 = (const float*)d_in[3];
  const float* wo  = (const float*)d_in[4];
  float* out = (float*)d_out;

  char* w = (char*)d_ws;
  int*   counts  = (int*)(w);
  int*   offsets = (int*)(w + 256);
  int*   tkidx   = (int*)(w + 1024);
  float* tkw     = (float*)(w + 1024 + 65536);
  int*   ltok    = (int*)(w + 1024 + 2*65536);
  float* lwt     = (float*)(w + 1024 + 3*65536);
  short* xbf  = (short*)(w + 524288);
  short* hbuf = xbf + (size_t)TT * DD;                     // 2T x M bf16
  short* w0t  = hbuf + (size_t)2 * TT * MM;
  short* w1t  = w0t + (size_t)NE * DD * MM;
  short* wot  = w1t + (size_t)NE * DD * MM;
  const size_t NEED_FULL = 524288ull + (size_t)TT*DD*2 + (size_t)2*TT*MM*2 + 3ull*NE*DD*MM*2;
  const bool full = (ws_size >= NEED_FULL);

  hipMemsetAsync(counts, 0, 64, stream);
  hipMemsetAsync(out, 0, sizeof(float) * (size_t)out_size, stream);

  cvt_kernel<<<1024, 256, 0, stream>>>(x, xbf, (size_t)TT * DD);
  gate_kernel<<<TT, 256, 0, stream>>>(x, gk, counts, tkidx, tkw);
  scatter_kernel<<<1, 256, 0, stream>>>(counts, offsets, tkidx, tkw, ltok, lwt);

  if (full) {
    tcvt_kernel<<<dim3(MM/64, DD/64, 24), 256, 0, stream>>>(wi0, wi1, wo, w0t, w1t, wot);
    gemm1_fast<<<dim3(MAXT_F, MM/128), 256, 0, stream>>>(xbf, w0t, w1t, offsets, ltok, lwt, hbuf);
    gemm2_fast<<<dim3(MAXT_F, DD/128), 256, 0, stream>>>(hbuf, wot, offsets, ltok, out);
  } else {
    dim3 g1(MAXT, MM / BN1), g2(MAXT, DD / BN2);
    gemm1_kernel<false><<<g1, 512, 0, stream>>>(xbf, nullptr, nullptr, wi0, wi1,
                                                offsets, ltok, lwt, hbuf);
    gemm2_kernel<false><<<g2, 256, 0, stream>>>(hbuf, nullptr, wo, offsets, ltok, out);
  }
}